// Round 6
// baseline (365.607 us; speedup 1.0000x reference)
//
#include <hip/hip_runtime.h>
#include <math.h>

#define D_MODEL 1024
#define NUM_HEADS 16
#define DK 64
#define BATCH 2
#define NSEQ 2048
#define MROWS (BATCH * NSEQ)   // 4096

typedef __attribute__((ext_vector_type(8))) short bf16x8;
typedef __attribute__((ext_vector_type(4))) short s16x4;
typedef __attribute__((ext_vector_type(4))) float f32x4;
typedef unsigned short u16;

static __device__ __forceinline__ u16 f2bf_rne(float x) {
    union { float f; unsigned u; } v; v.f = x;
    unsigned r = v.u + 0x7fffu + ((v.u >> 16) & 1u);
    return (u16)(r >> 16);
}
static __device__ __forceinline__ void split_bf16(float x, u16& hi, u16& lo) {
    union { float f; unsigned u; } v; v.f = x;
    unsigned hb = v.u & 0xffff0000u;
    hi = (u16)(hb >> 16);
    union { unsigned u; float f; } hv; hv.u = hb;
    lo = f2bf_rne(x - hv.f);
}

#define AS1 __attribute__((address_space(1)))
#define AS3 __attribute__((address_space(3)))
static __device__ __forceinline__ void gl_lds16(const void* g, void* l) {
    __builtin_amdgcn_global_load_lds((AS1 void*)(uintptr_t)g, (AS3 void*)l, 16, 0, 0);
}

// ---------------------------------------------------------------------------
// fp32 -> split bf16 planes, up to 4 tensors per launch (blockIdx.y).
// ---------------------------------------------------------------------------
struct SplitN { const float* src[4]; u16* h[4]; u16* l[4]; };
__global__ __launch_bounds__(256)
void split_multi(SplitN args, int n8)
{
    const int w = blockIdx.y;
    const int i = blockIdx.x * 256 + threadIdx.x;
    if (i >= n8) return;
    const float* src = args.src[w];
    float4 a = ((const float4*)src)[2 * i];
    float4 b = ((const float4*)src)[2 * i + 1];
    float x[8] = {a.x, a.y, a.z, a.w, b.x, b.y, b.z, b.w};
    u16 hh[8], ll[8];
#pragma unroll
    for (int j = 0; j < 8; ++j) split_bf16(x[j], hh[j], ll[j]);
    *(uint4*)(args.h[w] + 8 * (size_t)i) = *(uint4*)hh;
    *(uint4*)(args.l[w] + 8 * (size_t)i) = *(uint4*)ll;
}

// ---------------------------------------------------------------------------
// MFMA GEMM v2, split-bf16 3-term: C = (A @ W^T + bias) * scale.
// MT = m-tiles per wave: MT=4 -> BM=128, MT=2 -> BM=64. BN=128, BK=32.
// 4 waves (2x2), wave tile (MT*16)x64. Per wave K-step: MT*4*3 MFMA,
// (MT+4)*2 ds_read_b128. Swizzle: 4 granules/row, slot = g ^ (row&3),
// applied on the global side of global_load_lds.
// mode 0: fp32 out. mode 1: split planes. mode 2 (MT=4): V -> per-head
// transposed single RNE plane Vt[b][h][d][n] via LDS re-transpose.
// ---------------------------------------------------------------------------
struct GemmDesc {
    const u16 *Ah, *Al, *Wh, *Wl;
    const float* bias;
    float* outF;
    u16 *outH, *outL;
    float scale;
    int mode;
};
struct GemmBatch { GemmDesc d[3]; };

template<int MT>
__global__ __launch_bounds__(256)
void gemm_mfma_v2(GemmBatch batch, int M, int N, int K)
{
    constexpr int BM = MT * 32;
    __shared__ u16 SM[(2 * BM + 2 * 128) * 32];
    u16* As_h = SM;
    u16* As_l = As_h + BM * 32;
    u16* Ws_h = As_l + BM * 32;
    u16* Ws_l = Ws_h + 128 * 32;

    const GemmDesc d = batch.d[blockIdx.z];
    const int tid  = threadIdx.x;
    const int wv   = tid >> 6, lane = tid & 63;
    const int quad = lane >> 4, lcol = lane & 15;
    const int bm = blockIdx.y * BM, bn = blockIdx.x * 128;
    const int wm = (wv >> 1) * (MT * 16), wn = (wv & 1) * 64;
    // staging: lane -> (row srow in 16-row group, slot lane&3); fetch granule g4
    const int srow = lane >> 2;
    const int g4o  = (((lane & 3) ^ (srow & 3)) << 3);   // u16 offset
    const int xk   = (lcol & 3);

    f32x4 acc[MT][4];
#pragma unroll
    for (int i = 0; i < MT; ++i)
#pragma unroll
        for (int j = 0; j < 4; ++j) acc[i][j] = (f32x4){0.f, 0.f, 0.f, 0.f};

    constexpr int AIPW = BM / 64;   // A instrs per wave per plane

    for (int k0 = 0; k0 < K; k0 += 32) {
        __syncthreads();
#pragma unroll
        for (int c = 0; c < AIPW; ++c) {
            const int rb = (wv * AIPW + c) * 16;
            gl_lds16(d.Ah + (size_t)(bm + rb + srow) * K + k0 + g4o, As_h + rb * 32);
            gl_lds16(d.Al + (size_t)(bm + rb + srow) * K + k0 + g4o, As_l + rb * 32);
        }
#pragma unroll
        for (int c = 0; c < 2; ++c) {
            const int rb = (wv * 2 + c) * 16;
            gl_lds16(d.Wh + (size_t)(bn + rb + srow) * K + k0 + g4o, Ws_h + rb * 32);
            gl_lds16(d.Wl + (size_t)(bn + rb + srow) * K + k0 + g4o, Ws_l + rb * 32);
        }
        __syncthreads();

        bf16x8 bh[4], bl[4];
#pragma unroll
        for (int j = 0; j < 4; ++j) {
            const int off = (wn + (j << 4) + lcol) * 32 + ((quad ^ xk) << 3);
            bh[j] = *(const bf16x8*)(Ws_h + off);
            bl[j] = *(const bf16x8*)(Ws_l + off);
        }
#pragma unroll
        for (int i = 0; i < MT; ++i) {
            const int off = (wm + (i << 4) + lcol) * 32 + ((quad ^ xk) << 3);
            bf16x8 ah = *(const bf16x8*)(As_h + off);
            bf16x8 al = *(const bf16x8*)(As_l + off);
#pragma unroll
            for (int j = 0; j < 4; ++j) {
                acc[i][j] = __builtin_amdgcn_mfma_f32_16x16x32_bf16(ah, bh[j], acc[i][j], 0, 0, 0);
                acc[i][j] = __builtin_amdgcn_mfma_f32_16x16x32_bf16(al, bh[j], acc[i][j], 0, 0, 0);
                acc[i][j] = __builtin_amdgcn_mfma_f32_16x16x32_bf16(ah, bl[j], acc[i][j], 0, 0, 0);
            }
        }
    }

    if constexpr (MT == 4) {
        if (batch.d[blockIdx.z].mode == 2) {
            // V path: two half-passes (one head each), LDS re-transpose.
            u16* T = SM;                      // [64][136] u16 = 17.4 KB
#pragma unroll
            for (int p = 0; p < 2; ++p) {
                __syncthreads();
                if ((wv & 1) == p) {
#pragma unroll
                    for (int j = 0; j < 4; ++j) {
                        const int cl = (j << 4) + lcol;              // d-local 0..63
                        const float bj = d.bias[bn + wn + (j << 4) + lcol];
#pragma unroll
                        for (int i = 0; i < 4; ++i) {
                            u16 pk[4];
#pragma unroll
                            for (int r = 0; r < 4; ++r)
                                pk[r] = f2bf_rne(acc[i][j][r] + bj);
                            *(ushort4*)(T + cl * 136 + wm + (i << 4) + quad * 4) = *(ushort4*)pk;
                        }
                    }
                }
                __syncthreads();
                const int dd = tid >> 2, nt = tid & 3;
                u16* dst = d.outH
                    + ((size_t)((bm >> 11) * NUM_HEADS + (bn >> 6) + p) * DK + dd) * NSEQ
                    + (bm & (NSEQ - 1)) + nt * 32;
                const u16* srcT = T + dd * 136 + nt * 32;
#pragma unroll
                for (int k = 0; k < 4; ++k)
                    ((uint4*)dst)[k] = *(const uint4*)(srcT + 8 * k);
            }
            return;
        }
    }

#pragma unroll
    for (int j = 0; j < 4; ++j) {
        const int col = bn + wn + (j << 4) + lcol;
        const float bj = d.bias[col];
#pragma unroll
        for (int i = 0; i < MT; ++i) {
#pragma unroll
            for (int r = 0; r < 4; ++r) {
                const int row = bm + wm + (i << 4) + quad * 4 + r;
                const float v = (acc[i][j][r] + bj) * d.scale;
                const size_t o = (size_t)row * N + col;
                if (d.mode == 0) {
                    d.outF[o] = v;
                } else {
                    u16 hi, lo;
                    split_bf16(v, hi, lo);
                    d.outH[o] = hi;
                    d.outL[o] = lo;
                }
            }
        }
    }
}

// ---------------------------------------------------------------------------
// Flash attention. 128 q/block, 4 waves x (2 sets of 16 q).
// S^T = K·Q^T (Q frags in regs as B-operands); per-lane softmax (q=lcol);
// P^T C-regs feed PV directly as B-frags (quad-consistent k-permutation);
// A = V^T frags from LDS. K/Vt staged via global_load_lds into unpadded
// [64][64] planes with 8-granule XOR swizzle (slot = g ^ (row&7)).
// LDS 24 KB, 2 barriers/tile, zero P LDS traffic.
// ---------------------------------------------------------------------------
__global__ __launch_bounds__(256)
void flash_attn(const u16* __restrict__ Qh_g, const u16* __restrict__ Ql_g,
                const u16* __restrict__ Kh_g, const u16* __restrict__ Kl_g,
                const u16* __restrict__ Vt_g,
                u16* __restrict__ Ch_g, u16* __restrict__ Cl_g)
{
    __shared__ __align__(16) u16 Ks_h[64 * 64], Ks_l[64 * 64], Vs[64 * 64];

    const int tid  = threadIdx.x;
    const int wv   = tid >> 6;
    const int lane = tid & 63;
    const int quad = lane >> 4;
    const int lcol = lane & 15;
    const int q0   = blockIdx.x << 7;
    const int h    = blockIdx.y;
    const int b    = blockIdx.z;
    const size_t hbase  = (size_t)b * NSEQ * D_MODEL + (size_t)h * DK;
    const size_t vtbase = (size_t)(b * NUM_HEADS + h) * DK * NSEQ;

    // Q B-fragments from global: B[k=d=quad*8+j][n=q=lcol]
    bf16x8 bQh[2][2], bQl[2][2];
#pragma unroll
    for (int s = 0; s < 2; ++s) {
        const u16* qh = Qh_g + hbase + (size_t)(q0 + wv * 32 + s * 16 + lcol) * D_MODEL;
        const u16* ql = Ql_g + hbase + (size_t)(q0 + wv * 32 + s * 16 + lcol) * D_MODEL;
#pragma unroll
        for (int c = 0; c < 2; ++c) {
            bQh[s][c] = *(const bf16x8*)(qh + c * 32 + quad * 8);
            bQl[s][c] = *(const bf16x8*)(ql + c * 32 + quad * 8);
        }
    }

    f32x4 Oacc[2][4];
#pragma unroll
    for (int s = 0; s < 2; ++s)
#pragma unroll
        for (int t = 0; t < 4; ++t) Oacc[s][t] = (f32x4){0.f, 0.f, 0.f, 0.f};
    float mrow[2] = {-INFINITY, -INFINITY};
    float lrow[2] = {0.f, 0.f};

    // staging lane mapping: row = lane>>3 (8 rows/instr), slot = lane&7,
    // fetched global granule = slot ^ row  -> LDS[r][p] holds granule p^(r&7)
    const int srow8 = lane >> 3;
    const int g8o   = (((lane & 7) ^ srow8) << 3);   // u16 offset
    const int xk    = (lcol & 7);

    for (int kt = 0; kt < NSEQ / 64; ++kt) {
        const int k0 = kt << 6;
        __syncthreads();
#pragma unroll
        for (int c = 0; c < 2; ++c) {
            const int rb = wv * 16 + c * 8;
            gl_lds16(Kh_g + hbase + (size_t)(k0 + rb + srow8) * D_MODEL + g8o, Ks_h + rb * 64);
            gl_lds16(Kl_g + hbase + (size_t)(k0 + rb + srow8) * D_MODEL + g8o, Ks_l + rb * 64);
            gl_lds16(Vt_g + vtbase + (size_t)(rb + srow8) * NSEQ + k0 + g8o, Vs + rb * 64);
        }
        __syncthreads();

        // S^T[key][q] = K·Q^T, 3-term split
        f32x4 S[2][4];
#pragma unroll
        for (int t = 0; t < 4; ++t) {
            const u16* krh = Ks_h + ((t << 4) + lcol) * 64;
            const u16* krl = Ks_l + ((t << 4) + lcol) * 64;
            const int s0 = ((quad ^ xk) << 3);
            const int s1 = (((4 + quad) ^ xk) << 3);
            bf16x8 aKh0 = *(const bf16x8*)(krh + s0);
            bf16x8 aKh1 = *(const bf16x8*)(krh + s1);
            bf16x8 aKl0 = *(const bf16x8*)(krl + s0);
            bf16x8 aKl1 = *(const bf16x8*)(krl + s1);
#pragma unroll
            for (int s = 0; s < 2; ++s) {
                f32x4 a = (f32x4){0.f, 0.f, 0.f, 0.f};
                a = __builtin_amdgcn_mfma_f32_16x16x32_bf16(aKh0, bQh[s][0], a, 0, 0, 0);
                a = __builtin_amdgcn_mfma_f32_16x16x32_bf16(aKh1, bQh[s][1], a, 0, 0, 0);
                a = __builtin_amdgcn_mfma_f32_16x16x32_bf16(aKl0, bQh[s][0], a, 0, 0, 0);
                a = __builtin_amdgcn_mfma_f32_16x16x32_bf16(aKl1, bQh[s][1], a, 0, 0, 0);
                a = __builtin_amdgcn_mfma_f32_16x16x32_bf16(aKh0, bQl[s][0], a, 0, 0, 0);
                a = __builtin_amdgcn_mfma_f32_16x16x32_bf16(aKh1, bQl[s][1], a, 0, 0, 0);
                S[s][t] = a;
            }
        }

        // per-lane online softmax + P packing
        bf16x8 pb[2][2];
#pragma unroll
        for (int s = 0; s < 2; ++s) {
            float m16 = -INFINITY;
#pragma unroll
            for (int t = 0; t < 4; ++t)
#pragma unroll
                for (int r = 0; r < 4; ++r) m16 = fmaxf(m16, S[s][t][r]);
            m16 = fmaxf(m16, __shfl_xor(m16, 16, 64));
            m16 = fmaxf(m16, __shfl_xor(m16, 32, 64));
            const float mn = fmaxf(mrow[s], m16);
            const float alpha = __expf(mrow[s] - mn);
            mrow[s] = mn;

            float p[4][4];
            float psum = 0.f;
#pragma unroll
            for (int t = 0; t < 4; ++t)
#pragma unroll
                for (int r = 0; r < 4; ++r) {
                    const float pv = __expf(S[s][t][r] - mn);
                    p[t][r] = pv;
                    psum += pv;
                }
            psum += __shfl_xor(psum, 16, 64);
            psum += __shfl_xor(psum, 32, 64);
            lrow[s] = alpha * lrow[s] + psum;

#pragma unroll
            for (int c = 0; c < 2; ++c) {
                bf16x8 v;
#pragma unroll
                for (int r = 0; r < 4; ++r) {
                    v[r]     = (short)f2bf_rne(p[2 * c][r]);
                    v[4 + r] = (short)f2bf_rne(p[2 * c + 1][r]);
                }
                pb[s][c] = v;
            }
#pragma unroll
            for (int t = 0; t < 4; ++t)
#pragma unroll
                for (int r = 0; r < 4; ++r) Oacc[s][t][r] *= alpha;
        }

        // O^T += V^T · P (A = swizzled V^T frags, B = pb)
#pragma unroll
        for (int dt = 0; dt < 4; ++dt) {
            const u16* vr = Vs + ((dt << 4) + lcol) * 64;
#pragma unroll
            for (int c = 0; c < 2; ++c) {
                const int s0 = (((c * 4 + (quad >> 1)) ^ xk) << 3) + ((quad & 1) << 2);
                s16x4 alo = *(const s16x4*)(vr + s0);
                s16x4 ahi = *(const s16x4*)(vr + (s0 ^ 16));
                bf16x8 aV;
#pragma unroll
                for (int r = 0; r < 4; ++r) { aV[r] = alo[r]; aV[4 + r] = ahi[r]; }
#pragma unroll
                for (int s = 0; s < 2; ++s)
                    Oacc[s][dt] = __builtin_amdgcn_mfma_f32_16x16x32_bf16(aV, pb[s][c], Oacc[s][dt], 0, 0, 0);
            }
        }
    }

    // epilogue: O^T rows d=16dt+4quad+r, col q=lcol; per-lane 1/l
#pragma unroll
    for (int s = 0; s < 2; ++s) {
        const float inv = 1.f / lrow[s];
        const size_t base = hbase + (size_t)(q0 + wv * 32 + s * 16 + lcol) * D_MODEL;
#pragma unroll
        for (int dt = 0; dt < 4; ++dt) {
            u16 hv[4], lv[4];
#pragma unroll
            for (int r = 0; r < 4; ++r)
                split_bf16(Oacc[s][dt][r] * inv, hv[r], lv[r]);
            const size_t o = base + (dt << 4) + quad * 4;
            *(ushort4*)(Ch_g + o) = *(ushort4*)hv;
            *(ushort4*)(Cl_g + o) = *(ushort4*)lv;
        }
    }
}

// ---------------------------------------------------------------------------
extern "C" void kernel_launch(void* const* d_in, const int* in_sizes, int n_in,
                              void* d_out, int out_size, void* d_ws, size_t ws_size,
                              hipStream_t stream)
{
    const float* query = (const float*)d_in[0];
    const float* key_i = (const float*)d_in[1];
    const float* value = (const float*)d_in[2];
    const float* w_q   = (const float*)d_in[3];
    const float* b_q   = (const float*)d_in[4];
    const float* w_k   = (const float*)d_in[5];
    const float* b_k   = (const float*)d_in[6];
    const float* w_v   = (const float*)d_in[7];
    const float* b_v   = (const float*)d_in[8];
    const float* w_o   = (const float*)d_in[9];
    const float* b_o   = (const float*)d_in[10];
    float* out = (float*)d_out;

    const size_t WE = (size_t)D_MODEL * D_MODEL;   // 1M
    const size_t AE = (size_t)MROWS * D_MODEL;     // 4M

    u16* p = (u16*)d_ws;
    u16* Wqh = p;            u16* Wql = Wqh + WE;
    u16* Wkh = Wql + WE;     u16* Wkl = Wkh + WE;
    u16* Wvh = Wkl + WE;     u16* Wvl = Wvh + WE;
    u16* Woh = Wvl + WE;     u16* Wol = Woh + WE;
    u16* base = Wol + WE;

    SplitN ws4;
    ws4.src[0] = w_q; ws4.h[0] = Wqh; ws4.l[0] = Wql;
    ws4.src[1] = w_k; ws4.h[1] = Wkh; ws4.l[1] = Wkl;
    ws4.src[2] = w_v; ws4.h[2] = Wvh; ws4.l[2] = Wvl;
    ws4.src[3] = w_o; ws4.h[3] = Woh; ws4.l[3] = Wol;
    split_multi<<<dim3((unsigned)(WE / 8 / 256), 4), 256, 0, stream>>>(ws4, (int)(WE / 8));

    const float qscale = 0.125f;
    dim3 fgrid(NSEQ / 128, NUM_HEADS, BATCH);          // (16,16,2)
    dim3 qkvgrid(D_MODEL / 128, MROWS / 128, 3);       // (8,32,3)
    dim3 outgrid(D_MODEL / 128, MROWS / 64, 1);        // (8,64,1)
    dim3 qkvgrid1(D_MODEL / 128, MROWS / 128, 1);
    const int an8 = (int)(AE / 8);

    const size_t fused_bytes = 2 * (8 * WE + 11 * AE);   // 104 MB
    if (ws_size >= fused_bytes) {
        u16* INqh = base;          u16* INql = INqh + AE;
        u16* INkh = INql + AE;     u16* INkl = INkh + AE;
        u16* INvh = INkl + AE;     u16* INvl = INvh + AE;
        u16* Qph  = INvl + AE;     u16* Qpl  = Qph + AE;
        u16* Kph  = Qpl + AE;      u16* Kpl  = Kph + AE;
        u16* VT   = Kpl + AE;
        u16* Ch   = INqh;          u16* Cl   = INql;    // alias, dead after QKV

        SplitN as3;
        as3.src[0] = query; as3.h[0] = INqh; as3.l[0] = INql;
        as3.src[1] = key_i; as3.h[1] = INkh; as3.l[1] = INkl;
        as3.src[2] = value; as3.h[2] = INvh; as3.l[2] = INvl;
        as3.src[3] = query; as3.h[3] = INqh; as3.l[3] = INql;  // unused
        split_multi<<<dim3((unsigned)(AE / 8 / 256), 3), 256, 0, stream>>>(as3, an8);

        GemmBatch gb;
        gb.d[0] = {INqh, INql, Wqh, Wql, b_q, nullptr, Qph, Qpl, qscale, 1};
        gb.d[1] = {INkh, INkl, Wkh, Wkl, b_k, nullptr, Kph, Kpl, 1.0f,   1};
        gb.d[2] = {INvh, INvl, Wvh, Wvl, b_v, nullptr, VT,  nullptr, 1.0f, 2};
        gemm_mfma_v2<4><<<qkvgrid, 256, 0, stream>>>(gb, MROWS, D_MODEL, D_MODEL);

        flash_attn<<<fgrid, 256, 0, stream>>>(Qph, Qpl, Kph, Kpl, VT, Ch, Cl);

        GemmBatch go;
        go.d[0] = {Ch, Cl, Woh, Wol, b_o, out, nullptr, nullptr, 1.0f, 0};
        gemm_mfma_v2<2><<<outgrid, 256, 0, stream>>>(go, MROWS, D_MODEL, D_MODEL);
    } else {
        u16* INh = base;           u16* INl = INh + AE;
        u16* Qph = INl + AE;       u16* Qpl = Qph + AE;
        u16* Kph = Qpl + AE;       u16* Kpl = Kph + AE;
        u16* VT  = Kpl + AE;
        u16* Ch  = INh;            u16* Cl  = INl;

        SplitN s1;
        s1.src[0] = query; s1.h[0] = INh; s1.l[0] = INl;
        s1.src[1] = s1.src[2] = s1.src[3] = query;
        s1.h[1] = s1.h[2] = s1.h[3] = INh; s1.l[1] = s1.l[2] = s1.l[3] = INl;

        GemmBatch g;
        s1.src[0] = query;
        split_multi<<<dim3((unsigned)(AE / 8 / 256), 1), 256, 0, stream>>>(s1, an8);
        g.d[0] = {INh, INl, Wqh, Wql, b_q, nullptr, Qph, Qpl, qscale, 1};
        gemm_mfma_v2<4><<<qkvgrid1, 256, 0, stream>>>(g, MROWS, D_MODEL, D_MODEL);

        s1.src[0] = key_i;
        split_multi<<<dim3((unsigned)(AE / 8 / 256), 1), 256, 0, stream>>>(s1, an8);
        g.d[0] = {INh, INl, Wkh, Wkl, b_k, nullptr, Kph, Kpl, 1.0f, 1};
        gemm_mfma_v2<4><<<qkvgrid1, 256, 0, stream>>>(g, MROWS, D_MODEL, D_MODEL);

        s1.src[0] = value;
        split_multi<<<dim3((unsigned)(AE / 8 / 256), 1), 256, 0, stream>>>(s1, an8);
        g.d[0] = {INh, INl, Wvh, Wvl, b_v, nullptr, VT, nullptr, 1.0f, 2};
        gemm_mfma_v2<4><<<qkvgrid1, 256, 0, stream>>>(g, MROWS, D_MODEL, D_MODEL);

        flash_attn<<<fgrid, 256, 0, stream>>>(Qph, Qpl, Kph, Kpl, VT, Ch, Cl);

        g.d[0] = {Ch, Cl, Woh, Wol, b_o, out, nullptr, nullptr, 1.0f, 0};
        gemm_mfma_v2<2><<<outgrid, 256, 0, stream>>>(g, MROWS, D_MODEL, D_MODEL);
    }
}